// Round 4
// baseline (526.892 us; speedup 1.0000x reference)
//
#include <hip/hip_runtime.h>
#include <hip/hip_bf16.h>

// Problem constants (fixed by the reference).
#define BB 32
#define SS 256
#define DD 256
#define UU 256
#define LL 16
#define DEG 16
#define NN (BB * SS)   // 8192 nodes
#define EE (NN * DEG)  // 131072 edges per branch
#define NSLICE 33      // slice 0 = self-loop, 1..16 = in labels, 17..32 = out labels
#define KMAIN (NSLICE * DD)   // 8448
#define KEXT 256              // ext cols: wsum/bias GEMM trick (33 used, rest 0)
#define KTOT (KMAIN + KEXT)   // 8704 = 34*256
#define KSPLIT 8
#define KS (KTOT / KSPLIT)    // 1088 = 17*64
#define TM 256                // rows (nodes) per block
#define BK 64                 // k step
#define NT (KS / BK)          // 17 k-tiles per block

using short8 = __attribute__((ext_vector_type(8))) short;  // 8 bf16 (4 VGPRs)
using f32x4  = __attribute__((ext_vector_type(4))) float;  // MFMA accumulator

// async global->LDS, 16B per lane, LDS dest = wave-uniform base + lane*16
#define GLDS(g, l)                                                        \
  __builtin_amdgcn_global_load_lds(                                       \
      (const __attribute__((address_space(1))) void*)(g),                 \
      (__attribute__((address_space(3))) void*)(l), 16, 0, 0)

__device__ __forceinline__ float bf2f(unsigned short v) {
  union { unsigned u; float f; } t;
  t.u = ((unsigned)v) << 16;
  return t.f;
}
__device__ __forceinline__ unsigned short f2bf(float f) {
  __hip_bfloat16 h = __float2bfloat16(f);
  return *(unsigned short*)&h;
}
__device__ __forceinline__ float sigm(float x) {
  return 1.f / (1.f + __expf(-x));
}

// ---------------------------------------------------------------------------
// K1: blocks [0,NN): x cast to bf16 + 3 gate dots.
// blocks [NN, NN+NSLICE*64): weight transpose Vt[u][z*256+d] = V_z[d][u].
// (ext bias columns of A are built in k_fused from CSR wsums; Vt ext rows
//  hold the biases, unchanged round-0 trick.)
// ---------------------------------------------------------------------------
__global__ __launch_bounds__(256) void k_pre(
    const float* __restrict__ src, const float* __restrict__ gin,
    const float* __restrict__ gout, const float* __restrict__ gloop,
    const float* __restrict__ Vin, const float* __restrict__ Vout,
    const float* __restrict__ Wself, const float* __restrict__ b_in,
    const float* __restrict__ b_out,
    __hip_bfloat16* __restrict__ x_bf, float* __restrict__ xg_in,
    float* __restrict__ xg_out, float* __restrict__ xg_loop,
    __hip_bfloat16* __restrict__ Vt) {
  int bid = blockIdx.x;
  if (bid < NN) {
    int n = bid;
    int b = n / SS, s = n % SS;
    int d = threadIdx.x;
    float v = src[(size_t)(s * BB + b) * DD + d];
    x_bf[(size_t)n * DD + d] = __float2bfloat16(v);
    float p0 = v * gin[d], p1 = v * gout[d], p2 = v * gloop[d];
#pragma unroll
    for (int o = 32; o > 0; o >>= 1) {
      p0 += __shfl_down(p0, o);
      p1 += __shfl_down(p1, o);
      p2 += __shfl_down(p2, o);
    }
    __shared__ float r0[4], r1[4], r2[4];
    int w = threadIdx.x >> 6, lane = threadIdx.x & 63;
    if (lane == 0) { r0[w] = p0; r1[w] = p1; r2[w] = p2; }
    __syncthreads();
    if (threadIdx.x == 0) {
      xg_in[n]   = r0[0] + r0[1] + r0[2] + r0[3];
      xg_out[n]  = r1[0] + r1[1] + r1[2] + r1[3];
      xg_loop[n] = r2[0] + r2[1] + r2[2] + r2[3];
    }
    return;
  }
  int t = bid - NN;
  int z = t >> 6;                 // 0..NSLICE
  int rem = t & 63;
  int bx = rem & 7, by = rem >> 3;
  int tid = threadIdx.x;
  int tx = tid & 31, ty = tid >> 5;
  if (z == NSLICE) {              // ext bias rows
    int u0 = bx * 32, j0 = by * 32;
#pragma unroll
    for (int i = 0; i < 4; i++) {
      int u = u0 + ty + i * 8, j = j0 + tx;
      float v = 0.f;
      if (j >= 1 && j <= LL)         v = b_in[(j - 1) * UU + u];
      else if (j > LL && j < NSLICE) v = b_out[(j - 1 - LL) * UU + u];
      Vt[(size_t)u * KTOT + KMAIN + j] = __float2bfloat16(v);
    }
    return;
  }
  __shared__ float tbuf[32][33];
  const float* srcM = (z == 0) ? Wself
                    : (z <= LL ? Vin  + (size_t)(z - 1)      * DD * UU
                               : Vout + (size_t)(z - 1 - LL) * DD * UU);
  int u0 = bx * 32, d0 = by * 32;
#pragma unroll
  for (int i = 0; i < 4; i++) {
    int dr = ty + i * 8;
    tbuf[dr][tx] = srcM[(size_t)(d0 + dr) * UU + u0 + tx];
  }
  __syncthreads();
#pragma unroll
  for (int i = 0; i < 4; i++) {
    int ur = ty + i * 8;
    Vt[(size_t)(u0 + ur) * KTOT + z * DD + d0 + tx] = __float2bfloat16(tbuf[tx][ur]);
  }
}

// ---------------------------------------------------------------------------
// K2: per-node edge lists sorted by slice (CSR). One block per node.
// es_src/es_w sorted by slice; e_start[n][z] = #edges with slice < z (z<=33);
// wl[n] = sigm(xg_loop)*mask_loop. (round-3 proven)
// ---------------------------------------------------------------------------
__global__ __launch_bounds__(64) void k_edges(
    const float* __restrict__ xg_in, const float* __restrict__ xg_out,
    const float* __restrict__ xg_loop,
    const float* __restrict__ b_ing, const float* __restrict__ b_outg,
    const int* __restrict__ arc_in, const int* __restrict__ arc_out,
    const int* __restrict__ lab_in, const int* __restrict__ lab_out,
    const float* __restrict__ mask_in, const float* __restrict__ mask_out,
    const float* __restrict__ mask_loop,
    int* __restrict__ es_src, float* __restrict__ es_w,
    unsigned char* __restrict__ e_start, float* __restrict__ wl) {
  __shared__ int u_sl[32], u_src[32];
  __shared__ float u_w[32];
  int n = blockIdx.x, tid = threadIdx.x;
  if (tid < 32) {
    int br = tid >> 4, k = tid & 15;
    int e = n * DEG + k;
    const int* a = br ? arc_out : arc_in;
    int l = (br ? lab_out : lab_in)[e];
    int srcn = a[e] * SS + a[EE + e];
    float g = (br ? xg_out : xg_in)[srcn] + (br ? b_outg : b_ing)[l];
    u_sl[tid] = 1 + br * LL + l;
    u_src[tid] = srcn;
    u_w[tid] = sigm(g) * (br ? mask_out : mask_in)[e];
  }
  __syncthreads();
  if (tid < 32) {
    int my = u_sl[tid];
    int rank = 0;
#pragma unroll
    for (int j = 0; j < 32; j++) {
      int oj = u_sl[j];
      rank += (oj < my || (oj == my && j < tid)) ? 1 : 0;
    }
    es_src[(size_t)n * 32 + rank] = u_src[tid];
    es_w[(size_t)n * 32 + rank] = u_w[tid];
  }
  if (tid < 34) {
    int cnt = 0;
#pragma unroll
    for (int j = 0; j < 32; j++) cnt += (u_sl[j] < tid) ? 1 : 0;
    e_start[(size_t)n * 34 + tid] = (unsigned char)cnt;
  }
  if (tid == 0) wl[n] = sigm(xg_loop[n]) * mask_loop[n];
}

// ---------------------------------------------------------------------------
// K3 (k_fused): GEMM with on-the-fly A-tile gather, WAVE-COOPERATIVE version.
// Fix vs round 3: each wave owns 32 rows of the A-tile; per edge the FULL
// wave reads x[src][dc+lane] (2 B/lane = 128 B contiguous = 2 line-requests)
// instead of per-thread scattered 16 B loads (~64 requests/instr). Register
// accumulate per node, one swizzled ds_write_b16 per node (same LDS layout
// as round 3's verified swizzle; wbase is a multiple of 8 so perm = i&7).
// Gather for tile t+1 runs AFTER tile t's MFMA (cross-wave overlap hides L2
// latency); B staged via GLDS double-buffer; one __syncthreads per tile.
// Everything else (B-path, MFMA, swizzle, epilogue) identical to round 3.
// grid (NN/TM=32, KSPLIT=8), 512 thr = 8 waves (2 wm x 4 wn).
// ---------------------------------------------------------------------------
__global__ __launch_bounds__(512, 2) void k_fused(
    const __hip_bfloat16* __restrict__ X, const __hip_bfloat16* __restrict__ Vt,
    const int* __restrict__ es_src, const float* __restrict__ es_w,
    const unsigned char* __restrict__ e_start, const float* __restrict__ wl,
    __hip_bfloat16* __restrict__ partial) {
  __shared__ __align__(16) __hip_bfloat16 As[2][TM * BK];
  __shared__ __align__(16) __hip_bfloat16 Bs[2][TM * BK];

  const int tid = threadIdx.x;
  const int w = tid >> 6, lane = tid & 63;
  const int wm = w >> 2, wn = w & 3;           // wave grid 2x4
  const int lrow = lane & 15, quad = lane >> 4;
  const int row0 = blockIdx.x * TM;
  const int kbeg = blockIdx.y * KS;
  const int wbase = w * 32;                    // this wave's A-tile rows

  const unsigned short* xp = (const unsigned short*)X;

  // B staging (global_load_lds, pre-swizzled source) — round-3 proven
  const int arow = tid >> 3;
  const int scol = ((tid & 7) ^ (arow & 7)) << 3;
  const __hip_bfloat16* srcB = Vt + (size_t)arow * KTOT + scol;

  // ds_read swizzled k-slot offsets for the two k-halves
  const int sc0 = ((quad ^ (lrow & 7)) << 3);
  const int sc1 = (((4 + quad) ^ (lrow & 7)) << 3);

  // gather LDS write base: row (wbase+i) byte = (wbase+i)*128
  //   + (((lane>>3) ^ (i&7))<<4) + ((lane&7)<<1)
  char* asBase0 = (char*)&As[0][0];
  char* asBase1 = (char*)&As[1][0];
  const int gw_lane = ((lane & 7) << 1);
  const int gw_hi = (lane >> 3);

#define STG_B(bufi, k0)                                                    \
  {                                                                        \
    _Pragma("unroll")                                                      \
    for (int r = 0; r < 4; ++r)                                            \
      GLDS(srcB + (size_t)(r * 64) * KTOT + (k0),                          \
           &Bs[bufi][r * 4096 + (w << 9)]);                                \
  }

#define GATHER_A(bufi, kg)                                                 \
  {                                                                        \
    char* adst = (bufi) ? asBase1 : asBase0;                               \
    const int zz = (kg) >> 8;                                              \
    if ((kg) >= KMAIN) {               /* ext tile: wsum columns */        \
      int j = (kg) - KMAIN + lane;                                         \
      bool jv = (j >= 1 && j < NSLICE);                                    \
      _Pragma("unroll 4")                                                  \
      for (int i = 0; i < 32; ++i) {                                       \
        int ng = row0 + wbase + i;                                         \
        float s = 0.f;                                                     \
        if (jv) {                                                          \
          const unsigned char* ep = e_start + (size_t)ng * 34;             \
          int st = ep[j], en = ep[j + 1];                                  \
          const float* wpp = es_w + (size_t)ng * 32;                       \
          for (int e2 = st; e2 < en; ++e2) s += wpp[e2];                   \
        }                                                                  \
        *(unsigned short*)(adst + (wbase + i) * 128 +                      \
                           ((gw_hi ^ (i & 7)) << 4) + gw_lane) = f2bf(s);  \
      }                                                                    \
    } else if (zz == 0) {              /* self-loop tile */                \
      int dcl = ((kg) & 255) + lane;                                       \
      _Pragma("unroll 4")                                                  \
      for (int i = 0; i < 32; ++i) {                                       \
        int ng = row0 + wbase + i;                                         \
        float a = wl[ng] * bf2f(xp[(size_t)ng * DD + dcl]);                \
        *(unsigned short*)(adst + (wbase + i) * 128 +                      \
                           ((gw_hi ^ (i & 7)) << 4) + gw_lane) = f2bf(a);  \
      }                                                                    \
    } else {                           /* edge slices */                   \
      int dcl = ((kg) & 255) + lane;                                       \
      _Pragma("unroll 4")                                                  \
      for (int i = 0; i < 32; ++i) {                                       \
        int ng = row0 + wbase + i;                                         \
        const unsigned char* ep = e_start + (size_t)ng * 34;               \
        int st = ep[zz], en = ep[zz + 1];                                  \
        const int* sp2 = es_src + (size_t)ng * 32;                         \
        const float* wp2 = es_w + (size_t)ng * 32;                         \
        float a = 0.f;                                                     \
        for (int e2 = st; e2 < en; ++e2)                                   \
          a += wp2[e2] * bf2f(xp[(size_t)sp2[e2] * DD + dcl]);             \
        *(unsigned short*)(adst + (wbase + i) * 128 +                      \
                           ((gw_hi ^ (i & 7)) << 4) + gw_lane) = f2bf(a);  \
      }                                                                    \
    }                                                                      \
  }

#define RD_A(DST, IBASE)                                                   \
  _Pragma("unroll")                                                        \
  for (int i = 0; i < 4; ++i) {                                            \
    int ro = (wm * 128 + ((IBASE) + i) * 16 + lrow) * BK;                  \
    DST[i][0] = *(const short8*)&as[ro + sc0];                             \
    DST[i][1] = *(const short8*)&as[ro + sc1];                             \
  }
#define RD_B(DST, JBASE)                                                   \
  _Pragma("unroll")                                                        \
  for (int j = 0; j < 2; ++j) {                                            \
    int ro = (wn * 64 + ((JBASE) + j) * 16 + lrow) * BK;                   \
    DST[j][0] = *(const short8*)&bs[ro + sc0];                             \
    DST[j][1] = *(const short8*)&bs[ro + sc1];                             \
  }
// swapped operands: D = B_frag x A_frag (C^T fragments, round-2/3 proven)
#define MFMA16(AF, BF, IOFF, JOFF)                                         \
  {                                                                        \
    _Pragma("unroll")                                                      \
    for (int i = 0; i < 4; ++i)                                            \
      _Pragma("unroll")                                                    \
      for (int j = 0; j < 2; ++j) {                                        \
        acc[(IOFF) + i][(JOFF) + j] =                                      \
            __builtin_amdgcn_mfma_f32_16x16x32_bf16(                       \
                BF[j][0], AF[i][0], acc[(IOFF) + i][(JOFF) + j], 0, 0, 0); \
        acc[(IOFF) + i][(JOFF) + j] =                                      \
            __builtin_amdgcn_mfma_f32_16x16x32_bf16(                       \
                BF[j][1], AF[i][1], acc[(IOFF) + i][(JOFF) + j], 0, 0, 0); \
      }                                                                    \
  }
#define MFMA_TILE(bufi)                                                    \
  {                                                                        \
    const __hip_bfloat16* as = &As[bufi][0];                               \
    const __hip_bfloat16* bs = &Bs[bufi][0];                               \
    short8 afA[4][2], afB[4][2], bfA[2][2], bfB[2][2];                     \
    RD_A(afA, 0);                                                          \
    RD_B(bfA, 0);                                                          \
    MFMA16(afA, bfA, 0, 0);                                                \
    RD_B(bfB, 2);                                                          \
    MFMA16(afA, bfB, 0, 2);                                                \
    RD_A(afB, 4);                                                          \
    MFMA16(afB, bfA, 4, 0);                                                \
    MFMA16(afB, bfB, 4, 2);                                                \
  }

  f32x4 acc[8][4] = {};

  // Prologue: build tile 0 (A gather, B async); barrier drains both.
  STG_B(0, kbeg);
  GATHER_A(0, kbeg);
  __syncthreads();

  for (int t = 0; t < NT; ++t) {
    const int cur = t & 1;
    if (t + 1 < NT) STG_B(cur ^ 1, kbeg + (t + 1) * BK);  // async B prefetch
    MFMA_TILE(cur);                                       // compute current
    if (t + 1 < NT) GATHER_A(cur ^ 1, kbeg + (t + 1) * BK);  // gather next A
    __syncthreads();                                      // drain GLDS + order
  }
#undef STG_B
#undef GATHER_A
#undef RD_A
#undef RD_B
#undef MFMA16
#undef MFMA_TILE

  // Swapped C/D layout: lane owns row n = ...+lrow, u = j*16 + quad*4..+3
  __hip_bfloat16* P = partial + (size_t)blockIdx.y * NN * UU;
  unsigned short* Pp = (unsigned short*)P;
#pragma unroll
  for (int i = 0; i < 8; ++i)
#pragma unroll
    for (int j = 0; j < 4; ++j) {
      int nr = row0 + wm * 128 + i * 16 + lrow;
      int u0 = wn * 64 + j * 16 + quad * 4;
      ushort4 o;
      o.x = f2bf(acc[i][j][0]); o.y = f2bf(acc[i][j][1]);
      o.z = f2bf(acc[i][j][2]); o.w = f2bf(acc[i][j][3]);
      *(ushort4*)&Pp[(size_t)nr * UU + u0] = o;
    }
}

// ---------------------------------------------------------------------------
// K4: reduce KSPLIT bf16 partials + relu + sent_mask + transpose (round-0).
// ---------------------------------------------------------------------------
__global__ __launch_bounds__(64) void k_finish(
    const __hip_bfloat16* __restrict__ partial, const float* __restrict__ sent,
    float* __restrict__ out) {
  int n = blockIdx.x, u4 = threadIdx.x * 4;
  size_t idx = (size_t)n * UU + u4;
  const unsigned short* pp = (const unsigned short*)partial;
  float a0 = 0.f, a1 = 0.f, a2 = 0.f, a3 = 0.f;
#pragma unroll
  for (int z = 0; z < KSPLIT; z++) {
    ushort4 v = *(const ushort4*)&pp[(size_t)z * NN * UU + idx];
    a0 += bf2f(v.x); a1 += bf2f(v.y); a2 += bf2f(v.z); a3 += bf2f(v.w);
  }
  int s = n % SS, b = n / SS;
  float sm = sent[s * BB + b];
  float4 o;
  o.x = fmaxf(a0, 0.f) * sm; o.y = fmaxf(a1, 0.f) * sm;
  o.z = fmaxf(a2, 0.f) * sm; o.w = fmaxf(a3, 0.f) * sm;
  *(float4*)&out[((size_t)s * BB + b) * UU + u4] = o;
}

extern "C" void kernel_launch(void* const* d_in, const int* in_sizes, int n_in,
                              void* d_out, int out_size, void* d_ws, size_t ws_size,
                              hipStream_t stream) {
  const float* src      = (const float*)d_in[0];
  const float* V_in     = (const float*)d_in[1];
  const float* b_in     = (const float*)d_in[2];
  const float* V_ing    = (const float*)d_in[3];
  const float* b_ing    = (const float*)d_in[4];
  const float* V_out    = (const float*)d_in[5];
  const float* b_out    = (const float*)d_in[6];
  const float* V_outg   = (const float*)d_in[7];
  const float* b_outg   = (const float*)d_in[8];
  const float* W_self   = (const float*)d_in[9];
  const float* W_selfg  = (const float*)d_in[10];
  const int* arc_in     = (const int*)d_in[11];
  const int* arc_out    = (const int*)d_in[12];
  const int* lab_in     = (const int*)d_in[13];
  const int* lab_out    = (const int*)d_in[14];
  const float* mask_in  = (const float*)d_in[15];
  const float* mask_out = (const float*)d_in[16];
  const float* mask_loop= (const float*)d_in[17];
  const float* sent     = (const float*)d_in[18];
  float* out = (float*)d_out;

  char* ws = (char*)d_ws;
  size_t off = 0;
  auto alloc = [&](size_t bytes) -> void* {
    void* p = ws + off;
    off += (bytes + 255) & ~(size_t)255;
    return p;
  };
  __hip_bfloat16* x_bf = (__hip_bfloat16*)alloc((size_t)NN * DD * 2);       // 4 MB
  __hip_bfloat16* Vt   = (__hip_bfloat16*)alloc((size_t)UU * KTOT * 2);     // 4.5 MB
  float* xg_in   = (float*)alloc(NN * 4);
  float* xg_out  = (float*)alloc(NN * 4);
  float* xg_loop = (float*)alloc(NN * 4);
  int*   es_src  = (int*)alloc((size_t)NN * 32 * 4);                        // 1 MB
  float* es_w    = (float*)alloc((size_t)NN * 32 * 4);                      // 1 MB
  unsigned char* e_start = (unsigned char*)alloc((size_t)NN * 34);          // 0.3 MB
  float* wl      = (float*)alloc((size_t)NN * 4);
  __hip_bfloat16* partial =
      (__hip_bfloat16*)alloc((size_t)KSPLIT * NN * UU * 2);                 // 34 MB

  k_pre<<<NN + (NSLICE + 1) * 64, 256, 0, stream>>>(
      src, V_ing, V_outg, W_selfg, V_in, V_out, W_self, b_in, b_out,
      x_bf, xg_in, xg_out, xg_loop, Vt);
  k_edges<<<NN, 64, 0, stream>>>(xg_in, xg_out, xg_loop, b_ing, b_outg,
                                 arc_in, arc_out, lab_in, lab_out,
                                 mask_in, mask_out, mask_loop,
                                 es_src, es_w, e_start, wl);
  k_fused<<<dim3(NN / TM, KSPLIT), 512, 0, stream>>>(
      x_bf, Vt, es_src, es_w, e_start, wl, partial);
  k_finish<<<NN, 64, 0, stream>>>(partial, sent, out);
}

// Round 5
// 261.868 us; speedup vs baseline: 2.0121x; 2.0121x over previous
//
#include <hip/hip_runtime.h>
#include <hip/hip_bf16.h>

// Problem constants (fixed by the reference).
#define BB 32
#define SS 256
#define DD 256
#define UU 256
#define LL 16
#define DEG 16
#define NN (BB * SS)   // 8192 nodes
#define EE (NN * DEG)  // 131072 edges per branch
#define NSLICE 33      // slice 0 = self-loop, 1..16 = in labels, 17..32 = out labels
#define KMAIN (NSLICE * DD)   // 8448
#define KEXT 256              // ext cols: wsum/bias GEMM trick (33 used, rest 0)
#define KTOT (KMAIN + KEXT)   // 8704 = 34*256
#define KSPLIT 8
#define KS (KTOT / KSPLIT)    // 1088 = 17*64
#define TM 256                // rows (nodes) per block
#define BK 64                 // k step
#define NT (KS / BK)          // 17 k-tiles per block

using short8 = __attribute__((ext_vector_type(8))) short;  // 8 bf16 (4 VGPRs)
using f32x4  = __attribute__((ext_vector_type(4))) float;  // MFMA accumulator

// async global->LDS, 16B per lane, LDS dest = wave-uniform base + lane*16
#define GLDS(g, l)                                                        \
  __builtin_amdgcn_global_load_lds(                                       \
      (const __attribute__((address_space(1))) void*)(g),                 \
      (__attribute__((address_space(3))) void*)(l), 16, 0, 0)

__device__ __forceinline__ float bf2f(unsigned short v) {
  union { unsigned u; float f; } t;
  t.u = ((unsigned)v) << 16;
  return t.f;
}
__device__ __forceinline__ unsigned short f2bf(float f) {
  __hip_bfloat16 h = __float2bfloat16(f);
  return *(unsigned short*)&h;
}
__device__ __forceinline__ float sigm(float x) {
  return 1.f / (1.f + __expf(-x));
}

// ---------------------------------------------------------------------------
// K1: blocks [0,NN): x cast to bf16 + 3 gate dots.
// blocks [NN, NN+(NSLICE+1)*64): weight transpose Vt[u][z*256+d] = V_z[d][u]
// plus ext bias rows Vt[u][KMAIN+j] = bias_all[j][u]. (round-0 proven)
// ---------------------------------------------------------------------------
__global__ __launch_bounds__(256) void k_pre(
    const float* __restrict__ src, const float* __restrict__ gin,
    const float* __restrict__ gout, const float* __restrict__ gloop,
    const float* __restrict__ Vin, const float* __restrict__ Vout,
    const float* __restrict__ Wself, const float* __restrict__ b_in,
    const float* __restrict__ b_out,
    __hip_bfloat16* __restrict__ x_bf, float* __restrict__ xg_in,
    float* __restrict__ xg_out, float* __restrict__ xg_loop,
    __hip_bfloat16* __restrict__ Vt) {
  int bid = blockIdx.x;
  if (bid < NN) {
    int n = bid;
    int b = n / SS, s = n % SS;
    int d = threadIdx.x;
    float v = src[(size_t)(s * BB + b) * DD + d];
    x_bf[(size_t)n * DD + d] = __float2bfloat16(v);
    float p0 = v * gin[d], p1 = v * gout[d], p2 = v * gloop[d];
#pragma unroll
    for (int o = 32; o > 0; o >>= 1) {
      p0 += __shfl_down(p0, o);
      p1 += __shfl_down(p1, o);
      p2 += __shfl_down(p2, o);
    }
    __shared__ float r0[4], r1[4], r2[4];
    int w = threadIdx.x >> 6, lane = threadIdx.x & 63;
    if (lane == 0) { r0[w] = p0; r1[w] = p1; r2[w] = p2; }
    __syncthreads();
    if (threadIdx.x == 0) {
      xg_in[n]   = r0[0] + r0[1] + r0[2] + r0[3];
      xg_out[n]  = r1[0] + r1[1] + r1[2] + r1[3];
      xg_loop[n] = r2[0] + r2[1] + r2[2] + r2[3];
    }
    return;
  }
  int t = bid - NN;
  int z = t >> 6;                 // 0..NSLICE
  int rem = t & 63;
  int bx = rem & 7, by = rem >> 3;
  int tid = threadIdx.x;
  int tx = tid & 31, ty = tid >> 5;
  if (z == NSLICE) {              // ext bias rows
    int u0 = bx * 32, j0 = by * 32;
#pragma unroll
    for (int i = 0; i < 4; i++) {
      int u = u0 + ty + i * 8, j = j0 + tx;
      float v = 0.f;
      if (j >= 1 && j <= LL)         v = b_in[(j - 1) * UU + u];
      else if (j > LL && j < NSLICE) v = b_out[(j - 1 - LL) * UU + u];
      Vt[(size_t)u * KTOT + KMAIN + j] = __float2bfloat16(v);
    }
    return;
  }
  __shared__ float tbuf[32][33];
  const float* srcM = (z == 0) ? Wself
                    : (z <= LL ? Vin  + (size_t)(z - 1)      * DD * UU
                               : Vout + (size_t)(z - 1 - LL) * DD * UU);
  int u0 = bx * 32, d0 = by * 32;
#pragma unroll
  for (int i = 0; i < 4; i++) {
    int dr = ty + i * 8;
    tbuf[dr][tx] = srcM[(size_t)(d0 + dr) * UU + u0 + tx];
  }
  __syncthreads();
#pragma unroll
  for (int i = 0; i < 4; i++) {
    int ur = ty + i * 8;
    Vt[(size_t)(u0 + ur) * KTOT + z * DD + d0 + tx] = __float2bfloat16(tbuf[tx][ur]);
  }
}

// ---------------------------------------------------------------------------
// K2: edge metadata, one block per node.
//  eswp[n][33]  : (src,int w-bits) pairs; slot 0 = self-loop (src=n, w=wl);
//                 slots 1+rank = edges sorted by slice.
//  e_se2[z][n]  : packed start|(end<<8) into eswp slots for slice z (z<34).
//  wsumT[n][256]: bf16 per-slice weight sums (cols 1..32), rest 0 -> the
//                 ext/bias k-tiles become plain vector loads in k_fused.
// ---------------------------------------------------------------------------
__global__ __launch_bounds__(64) void k_edges(
    const float* __restrict__ xg_in, const float* __restrict__ xg_out,
    const float* __restrict__ xg_loop,
    const float* __restrict__ b_ing, const float* __restrict__ b_outg,
    const int* __restrict__ arc_in, const int* __restrict__ arc_out,
    const int* __restrict__ lab_in, const int* __restrict__ lab_out,
    const float* __restrict__ mask_in, const float* __restrict__ mask_out,
    const float* __restrict__ mask_loop,
    int2* __restrict__ eswp, unsigned short* __restrict__ e_se2,
    unsigned short* __restrict__ wsumT) {
  __shared__ int u_sl[32];
  __shared__ int u_src[32];
  __shared__ float u_w[32];
  int n = blockIdx.x, tid = threadIdx.x;
  if (tid < 32) {
    int br = tid >> 4, k = tid & 15;
    int e = n * DEG + k;
    const int* a = br ? arc_out : arc_in;
    int l = (br ? lab_out : lab_in)[e];
    int srcn = a[e] * SS + a[EE + e];
    float g = (br ? xg_out : xg_in)[srcn] + (br ? b_outg : b_ing)[l];
    u_sl[tid] = 1 + br * LL + l;
    u_src[tid] = srcn;
    u_w[tid] = sigm(g) * (br ? mask_out : mask_in)[e];
  }
  __syncthreads();
  if (tid < 32) {
    int my = u_sl[tid];
    int rank = 0;
#pragma unroll
    for (int j = 0; j < 32; j++) {
      int oj = u_sl[j];
      rank += (oj < my || (oj == my && j < tid)) ? 1 : 0;
    }
    int2 v;
    v.x = u_src[tid];
    v.y = __float_as_int(u_w[tid]);
    eswp[(size_t)n * 33 + 1 + rank] = v;
  }
  if (tid == 63) {
    float wlv = sigm(xg_loop[n]) * mask_loop[n];
    int2 v;
    v.x = n;
    v.y = __float_as_int(wlv);
    eswp[(size_t)n * 33] = v;
  }
  if (tid < 34) {
    int c1 = 0, c2 = 0;
#pragma unroll
    for (int j = 0; j < 32; j++) {
      c1 += (u_sl[j] < tid) ? 1 : 0;
      c2 += (u_sl[j] < tid + 1) ? 1 : 0;
    }
    int st = (tid == 0) ? 0 : 1 + c1;
    int en = (tid == 0) ? 1 : 1 + c2;
    e_se2[(size_t)tid * NN + n] = (unsigned short)(st | (en << 8));
  }
  for (int c = tid; c < 256; c += 64) {
    float s = 0.f;
    if (c >= 1 && c < NSLICE) {
#pragma unroll
      for (int j = 0; j < 32; j++) s += (u_sl[j] == c) ? u_w[j] : 0.f;
    }
    wsumT[(size_t)n * 256 + c] = f2bf(s);
  }
}

// ---------------------------------------------------------------------------
// K3 (k_fused): GEMM with on-the-fly A-tile gather, SUBGROUP-cooperative.
// Lane -> (row = wbase + rg*8 + (lane>>3), 16B chunk = lane&7): 8 lanes read
// one edge-row's 128B chunk contiguously (16 lines/instr, 8x fewer requests
// than R3; fully parallel issue, unlike R4's serial per-row loops).
// Metadata: e_se2 window (5 slices) staged in LDS once; slot-0 edge preloaded
// predicated one tile ahead (ISSUE before MFMA, FINISH after = T14); rare
// same-slice extras in a short tail loop. Ext tiles = one dwordx4 from wsumT.
// B/MFMA/swizzle/epilogue verbatim from R3/R4 (proven). 2-phase dbuf,
// grid (NN/TM=32, KSPLIT=8), 512 thr = 8 waves (2 wm x 4 wn).
// ---------------------------------------------------------------------------
__global__ __launch_bounds__(512, 2) void k_fused(
    const __hip_bfloat16* __restrict__ X, const __hip_bfloat16* __restrict__ Vt,
    const int2* __restrict__ eswp, const unsigned short* __restrict__ e_se2,
    const unsigned short* __restrict__ wsT,
    __hip_bfloat16* __restrict__ partial) {
  __shared__ __align__(16) __hip_bfloat16 As[2][TM * BK];
  __shared__ __align__(16) __hip_bfloat16 Bs[2][TM * BK];
  __shared__ unsigned short ese_s[5 * 256];

  const int tid = threadIdx.x;
  const int w = tid >> 6, lane = tid & 63;
  const int wm = w >> 2, wn = w & 3;           // wave grid 2x4
  const int lrow = lane & 15, quad = lane >> 4;
  const int row0 = blockIdx.x * TM;
  const int kbeg = blockIdx.y * KS;
  const int wbase = w * 32;                    // this wave's A-tile rows
  const int rsub = lane >> 3, dsub = lane & 7; // gather subgroup mapping

  const unsigned short* xp = (const unsigned short*)X;

  // B staging (global_load_lds, pre-swizzled source) — proven
  const int arow = tid >> 3;
  const int scol = ((tid & 7) ^ (arow & 7)) << 3;
  const __hip_bfloat16* srcB = Vt + (size_t)arow * KTOT + scol;

  // ds_read swizzled k-slot offsets for the two k-halves
  const int sc0 = ((quad ^ (lrow & 7)) << 3);
  const int sc1 = (((4 + quad) ^ (lrow & 7)) << 3);

  char* asB0 = (char*)&As[0][0];
  char* asB1 = (char*)&As[1][0];

  // gather state (static-indexed arrays; rule #20)
  int kgI = 0;
  unsigned short se_[4];
  float w0_[4];
  short8 x0_[4];

#define STG_B(bufi, k0)                                                    \
  {                                                                        \
    _Pragma("unroll")                                                      \
    for (int r = 0; r < 4; ++r)                                            \
      GLDS(srcB + (size_t)(r * 64) * KTOT + (k0),                          \
           &Bs[bufi][r * 4096 + (w << 9)]);                                \
  }

#define ISSUE(kg)                                                          \
  {                                                                        \
    kgI = (kg);                                                            \
    const int zi = (kgI >> 8) - z_lo;                                      \
    const bool ext_ = kgI >= KMAIN;                                        \
    const int dgl = (kgI & 255) + (dsub << 3);                             \
    _Pragma("unroll")                                                      \
    for (int rg = 0; rg < 4; ++rg) {                                       \
      int row_l = wbase + rg * 8 + rsub;                                   \
      if (ext_) {                                                          \
        se_[rg] = 0x100;  /* st=0,cnt=1 */                                 \
        w0_[rg] = 1.f;                                                     \
        x0_[rg] = *(const short8*)&wsT[(size_t)(row0 + row_l) * 256 + dgl];\
      } else {                                                             \
        unsigned short se = ese_s[zi * 256 + row_l];                       \
        se_[rg] = se;                                                      \
        int st = se & 255, cnt = (se >> 8) - st;                           \
        if (cnt > 0) {                                                     \
          int2 sw = eswp[(size_t)(row0 + row_l) * 33 + st];                \
          w0_[rg] = __int_as_float(sw.y);                                  \
          x0_[rg] = *(const short8*)&xp[(size_t)sw.x * DD + dgl];          \
        }                                                                  \
      }                                                                    \
    }                                                                      \
  }

#define FINISH(bufi)                                                       \
  {                                                                        \
    char* adst = (bufi) ? asB1 : asB0;                                     \
    const int dgl = (kgI & 255) + (dsub << 3);                             \
    _Pragma("unroll")                                                      \
    for (int rg = 0; rg < 4; ++rg) {                                       \
      int row_l = wbase + rg * 8 + rsub;                                   \
      int st = se_[rg] & 255, cnt = (se_[rg] >> 8) - st;                   \
      float a[8];                                                          \
      _Pragma("unroll")                                                    \
      for (int d = 0; d < 8; ++d) a[d] = 0.f;                              \
      if (cnt > 0) {                                                       \
        float ww = w0_[rg];                                                \
        _Pragma("unroll")                                                  \
        for (int d = 0; d < 8; ++d)                                        \
          a[d] = ww * bf2f((unsigned short)x0_[rg][d]);                    \
      }                                                                    \
      for (int e2 = 1; e2 < cnt; ++e2) {   /* rare extras */               \
        int2 sw = eswp[(size_t)(row0 + row_l) * 33 + st + e2];             \
        short8 xv = *(const short8*)&xp[(size_t)sw.x * DD + dgl];          \
        float ww = __int_as_float(sw.y);                                   \
        _Pragma("unroll")                                                  \
        for (int d = 0; d < 8; ++d)                                        \
          a[d] += ww * bf2f((unsigned short)xv[d]);                        \
      }                                                                    \
      short8 p;                                                            \
      _Pragma("unroll")                                                    \
      for (int d = 0; d < 8; ++d) p[d] = (short)f2bf(a[d]);                \
      *(short8*)(adst + row_l * 128 + ((dsub ^ (row_l & 7)) << 4)) = p;    \
    }                                                                      \
  }

#define RD_A(DST, IBASE)                                                   \
  _Pragma("unroll")                                                        \
  for (int i = 0; i < 4; ++i) {                                            \
    int ro = (wm * 128 + ((IBASE) + i) * 16 + lrow) * BK;                  \
    DST[i][0] = *(const short8*)&as[ro + sc0];                             \
    DST[i][1] = *(const short8*)&as[ro + sc1];                             \
  }
#define RD_B(DST, JBASE)                                                   \
  _Pragma("unroll")                                                        \
  for (int j = 0; j < 2; ++j) {                                            \
    int ro = (wn * 64 + ((JBASE) + j) * 16 + lrow) * BK;                   \
    DST[j][0] = *(const short8*)&bs[ro + sc0];                             \
    DST[j][1] = *(const short8*)&bs[ro + sc1];                             \
  }
// swapped operands: D = B_frag x A_frag (C^T fragments, proven)
#define MFMA16(AF, BF, IOFF, JOFF)                                         \
  {                                                                        \
    _Pragma("unroll")                                                      \
    for (int i = 0; i < 4; ++i)                                            \
      _Pragma("unroll")                                                    \
      for (int j = 0; j < 2; ++j) {                                        \
        acc[(IOFF) + i][(JOFF) + j] =                                      \
            __builtin_amdgcn_mfma_f32_16x16x32_bf16(                       \
                BF[j][0], AF[i][0], acc[(IOFF) + i][(JOFF) + j], 0, 0, 0); \
        acc[(IOFF) + i][(JOFF) + j] =                                      \
            __builtin_amdgcn_mfma_f32_16x16x32_bf16(                       \
                BF[j][1], AF[i][1], acc[(IOFF) + i][(JOFF) + j], 0, 0, 0); \
      }                                                                    \
  }
// B frags re-read per quadrant to cut peak VGPR (keeps 2 waves/SIMD)
#define MFMA_TILE(bufi)                                                    \
  {                                                                        \
    const __hip_bfloat16* as = &As[bufi][0];                               \
    const __hip_bfloat16* bs = &Bs[bufi][0];                               \
    short8 af[4][2], bf_[2][2];                                            \
    RD_A(af, 0);                                                           \
    RD_B(bf_, 0);                                                          \
    MFMA16(af, bf_, 0, 0);                                                 \
    RD_B(bf_, 2);                                                          \
    MFMA16(af, bf_, 0, 2);                                                 \
    RD_A(af, 4);                                                           \
    RD_B(bf_, 0);                                                          \
    MFMA16(af, bf_, 4, 0);                                                 \
    RD_B(bf_, 2);                                                          \
    MFMA16(af, bf_, 4, 2);                                                 \
  }

  // Prologue: stage e_se2 window into LDS, then build tile 0.
  const int z_lo = kbeg >> 8;
  for (int i = tid; i < 5 * 256; i += 512) {
    ese_s[i] = e_se2[(size_t)(z_lo + (i >> 8)) * NN + row0 + (i & 255)];
  }
  __syncthreads();

  f32x4 acc[8][4] = {};
  STG_B(0, kbeg);
  ISSUE(kbeg);
  FINISH(0);
  __syncthreads();

  for (int t = 0; t < NT; ++t) {
    const int cur = t & 1;
    if (t + 1 < NT) {
      STG_B(cur ^ 1, kbeg + (t + 1) * BK);  // async B prefetch
      ISSUE(kbeg + (t + 1) * BK);           // gather loads for next A-tile
    }
    MFMA_TILE(cur);                         // compute current
    if (t + 1 < NT) FINISH(cur ^ 1);        // consume gathers, write next A
    __syncthreads();                        // drain GLDS + order buffers
  }
#undef STG_B
#undef ISSUE
#undef FINISH
#undef RD_A
#undef RD_B
#undef MFMA16
#undef MFMA_TILE

  // Swapped C/D layout: lane owns row n = ...+lrow, u = j*16 + quad*4..+3
  __hip_bfloat16* P = partial + (size_t)blockIdx.y * NN * UU;
  unsigned short* Pp = (unsigned short*)P;
#pragma unroll
  for (int i = 0; i < 8; ++i)
#pragma unroll
    for (int j = 0; j < 4; ++j) {
      int nr = row0 + wm * 128 + i * 16 + lrow;
      int u0 = wn * 64 + j * 16 + quad * 4;
      ushort4 o;
      o.x = f2bf(acc[i][j][0]); o.y = f2bf(acc[i][j][1]);
      o.z = f2bf(acc[i][j][2]); o.w = f2bf(acc[i][j][3]);
      *(ushort4*)&Pp[(size_t)nr * UU + u0] = o;
    }
}

// ---------------------------------------------------------------------------
// K4: reduce KSPLIT bf16 partials + relu + sent_mask + transpose (round-0).
// ---------------------------------------------------------------------------
__global__ __launch_bounds__(64) void k_finish(
    const __hip_bfloat16* __restrict__ partial, const float* __restrict__ sent,
    float* __restrict__ out) {
  int n = blockIdx.x, u4 = threadIdx.x * 4;
  size_t idx = (size_t)n * UU + u4;
  const unsigned short* pp = (const unsigned short*)partial;
  float a0 = 0.f, a1 = 0.f, a2 = 0.f, a3 = 0.f;
#pragma unroll
  for (int z = 0; z < KSPLIT; z++) {
    ushort4 v = *(const ushort4*)&pp[(size_t)z * NN * UU + idx];
    a0 += bf2f(v.x); a1 += bf2f(v.y); a2 += bf2f(v.z); a3 += bf2f(v.w);
  }
  int s = n % SS, b = n / SS;
  float sm = sent[s * BB + b];
  float4 o;
  o.x = fmaxf(a0, 0.f) * sm; o.y = fmaxf(a1, 0.f) * sm;
  o.z = fmaxf(a2, 0.f) * sm; o.w = fmaxf(a3, 0.f) * sm;
  *(float4*)&out[((size_t)s * BB + b) * UU + u4] = o;
}

extern "C" void kernel_launch(void* const* d_in, const int* in_sizes, int n_in,
                              void* d_out, int out_size, void* d_ws, size_t ws_size,
                              hipStream_t stream) {
  const float* src      = (const float*)d_in[0];
  const float* V_in     = (const float*)d_in[1];
  const float* b_in     = (const float*)d_in[2];
  const float* V_ing    = (const float*)d_in[3];
  const float* b_ing    = (const float*)d_in[4];
  const float* V_out    = (const float*)d_in[5];
  const float* b_out    = (const float*)d_in[6];
  const float* V_outg   = (const float*)d_in[7];
  const float* b_outg   = (const float*)d_in[8];
  const float* W_self   = (const float*)d_in[9];
  const float* W_selfg  = (const float*)d_in[10];
  const int* arc_in     = (const int*)d_in[11];
  const int* arc_out    = (const int*)d_in[12];
  const int* lab_in     = (const int*)d_in[13];
  const int* lab_out    = (const int*)d_in[14];
  const float* mask_in  = (const float*)d_in[15];
  const float* mask_out = (const float*)d_in[16];
  const float* mask_loop= (const float*)d_in[17];
  const float* sent     = (const float*)d_in[18];
  float* out = (float*)d_out;

  char* ws = (char*)d_ws;
  size_t off = 0;
  auto alloc = [&](size_t bytes) -> void* {
    void* p = ws + off;
    off += (bytes + 255) & ~(size_t)255;
    return p;
  };
  __hip_bfloat16* x_bf = (__hip_bfloat16*)alloc((size_t)NN * DD * 2);       // 4 MB
  __hip_bfloat16* Vt   = (__hip_bfloat16*)alloc((size_t)UU * KTOT * 2);     // 4.5 MB
  float* xg_in   = (float*)alloc(NN * 4);
  float* xg_out  = (float*)alloc(NN * 4);
  float* xg_loop = (float*)alloc(NN * 4);
  int2* eswp = (int2*)alloc((size_t)NN * 33 * 8);                           // 2.2 MB
  unsigned short* e_se2 = (unsigned short*)alloc((size_t)34 * NN * 2);      // 0.6 MB
  unsigned short* wsumT = (unsigned short*)alloc((size_t)NN * 256 * 2);     // 4 MB
  __hip_bfloat16* partial =
      (__hip_bfloat16*)alloc((size_t)KSPLIT * NN * UU * 2);                 // 34 MB

  k_pre<<<NN + (NSLICE + 1) * 64, 256, 0, stream>>>(
      src, V_ing, V_outg, W_selfg, V_in, V_out, W_self, b_in, b_out,
      x_bf, xg_in, xg_out, xg_loop, Vt);
  k_edges<<<NN, 64, 0, stream>>>(xg_in, xg_out, xg_loop, b_ing, b_outg,
                                 arc_in, arc_out, lab_in, lab_out,
                                 mask_in, mask_out, mask_loop,
                                 eswp, e_se2, wsumT);
  k_fused<<<dim3(NN / TM, KSPLIT), 512, 0, stream>>>(
      x_bf, Vt, eswp, e_se2, wsumT, partial);
  k_finish<<<NN, 64, 0, stream>>>(partial, sent, out);
}

// Round 6
// 186.977 us; speedup vs baseline: 2.8180x; 1.4005x over previous
//
#include <hip/hip_runtime.h>
#include <hip/hip_bf16.h>

// Problem constants (fixed by the reference).
#define BB 32
#define SS 256
#define DD 256
#define UU 256
#define LL 16
#define DEG 16
#define NN (BB * SS)   // 8192 nodes
#define EE (NN * DEG)  // 131072 edges per branch
#define NSLICE 33      // slice 0 = self-loop, 1..16 = in labels, 17..32 = out labels
#define KMAIN (NSLICE * DD)   // 8448
#define KEXT 256              // ext cols: wsum/bias GEMM trick (33 used, rest 0)
#define KTOT (KMAIN + KEXT)   // 8704 = 34*256
#define KSPLIT 8
#define KS (KTOT / KSPLIT)    // 1088 = 17*64
#define TM 256                // GEMM row tile
#define TN 256                // GEMM col tile (= UU, full)
#define BK 64                 // GEMM k step
#define NTILES (KS / BK)      // 17 k-tiles per block

using short8 = __attribute__((ext_vector_type(8))) short;  // 8 bf16 (4 VGPRs)
using f32x4  = __attribute__((ext_vector_type(4))) float;  // MFMA accumulator

// async global->LDS, 16B per lane, LDS dest = wave-uniform base + lane*16
#define GLDS(g, l)                                                        \
  __builtin_amdgcn_global_load_lds(                                       \
      (const __attribute__((address_space(1))) void*)(g),                 \
      (__attribute__((address_space(3))) void*)(l), 16, 0, 0)

__device__ __forceinline__ float bf2f(unsigned short v) {
  union { unsigned u; float f; } t;
  t.u = ((unsigned)v) << 16;
  return t.f;
}
__device__ __forceinline__ unsigned short f2bf(float f) {
  __hip_bfloat16 h = __float2bfloat16(f);
  return *(unsigned short*)&h;
}
__device__ __forceinline__ float sigm(float x) {
  return 1.f / (1.f + __expf(-x));
}

// ---------------------------------------------------------------------------
// K1 (merged): blocks [0,NN): prep (x cast + 3 gate dots).
// blocks [NN, NN+(NSLICE+1)*64): weight transpose + ext bias rows.
// Verbatim from the 184.9 us build (round 1).
// ---------------------------------------------------------------------------
__global__ __launch_bounds__(256) void k_pre(
    const float* __restrict__ src, const float* __restrict__ gin,
    const float* __restrict__ gout, const float* __restrict__ gloop,
    const float* __restrict__ Vin, const float* __restrict__ Vout,
    const float* __restrict__ Wself, const float* __restrict__ b_in,
    const float* __restrict__ b_out,
    __hip_bfloat16* __restrict__ x_bf, float* __restrict__ xg_in,
    float* __restrict__ xg_out, float* __restrict__ xg_loop,
    __hip_bfloat16* __restrict__ Vt) {
  int bid = blockIdx.x;
  if (bid < NN) {
    int n = bid;
    int b = n / SS, s = n % SS;
    int d = threadIdx.x;
    float v = src[(size_t)(s * BB + b) * DD + d];
    x_bf[(size_t)n * DD + d] = __float2bfloat16(v);
    float p0 = v * gin[d], p1 = v * gout[d], p2 = v * gloop[d];
#pragma unroll
    for (int o = 32; o > 0; o >>= 1) {
      p0 += __shfl_down(p0, o);
      p1 += __shfl_down(p1, o);
      p2 += __shfl_down(p2, o);
    }
    __shared__ float r0[4], r1[4], r2[4];
    int w = threadIdx.x >> 6, lane = threadIdx.x & 63;
    if (lane == 0) { r0[w] = p0; r1[w] = p1; r2[w] = p2; }
    __syncthreads();
    if (threadIdx.x == 0) {
      xg_in[n]   = r0[0] + r0[1] + r0[2] + r0[3];
      xg_out[n]  = r1[0] + r1[1] + r1[2] + r1[3];
      xg_loop[n] = r2[0] + r2[1] + r2[2] + r2[3];
    }
    return;
  }
  int t = bid - NN;
  int z = t >> 6;                 // 0..NSLICE
  int rem = t & 63;
  int bx = rem & 7, by = rem >> 3;
  int tid = threadIdx.x;
  int tx = tid & 31, ty = tid >> 5;
  if (z == NSLICE) {              // ext bias rows: Vt[u][KMAIN+j] = bias_all[j][u]
    int u0 = bx * 32, j0 = by * 32;
#pragma unroll
    for (int i = 0; i < 4; i++) {
      int u = u0 + ty + i * 8, j = j0 + tx;
      float v = 0.f;
      if (j >= 1 && j <= LL)         v = b_in[(j - 1) * UU + u];
      else if (j > LL && j < NSLICE) v = b_out[(j - 1 - LL) * UU + u];
      Vt[(size_t)u * KTOT + KMAIN + j] = __float2bfloat16(v);
    }
    return;
  }
  __shared__ float tbuf[32][33];
  const float* srcM = (z == 0) ? Wself
                    : (z <= LL ? Vin  + (size_t)(z - 1)      * DD * UU
                               : Vout + (size_t)(z - 1 - LL) * DD * UU);
  int u0 = bx * 32, d0 = by * 32;
#pragma unroll
  for (int i = 0; i < 4; i++) {
    int dr = ty + i * 8;
    tbuf[dr][tx] = srcM[(size_t)(d0 + dr) * UU + u0 + tx];
  }
  __syncthreads();
#pragma unroll
  for (int i = 0; i < 4; i++) {
    int ur = ty + i * 8;
    Vt[(size_t)(u0 + ur) * KTOT + z * DD + d0 + tx] = __float2bfloat16(tbuf[tx][ur]);
  }
}

// ---------------------------------------------------------------------------
// K3: aggregation, one WAVE per dst node (round-0/1 proven; streaming writes
// of Y at near-HBM rate beat every fused-gather variant tried in R3-R5).
// ---------------------------------------------------------------------------
__global__ __launch_bounds__(64) void k_agg(
    const __hip_bfloat16* __restrict__ x,
    const float* __restrict__ xg_in, const float* __restrict__ xg_out,
    const float* __restrict__ xg_loop,
    const float* __restrict__ b_ing, const float* __restrict__ b_outg,
    const int* __restrict__ arc_in, const int* __restrict__ arc_out,
    const int* __restrict__ lab_in, const int* __restrict__ lab_out,
    const float* __restrict__ mask_in, const float* __restrict__ mask_out,
    const float* __restrict__ mask_loop,
    __hip_bfloat16* __restrict__ Y) {
  __shared__ int u_sl[32], u_src[32];
  __shared__ float u_w[32];
  __shared__ int s_sl[32], s_src[32];
  __shared__ float s_w[32];
  __shared__ float s_wsum[NSLICE];
  int n = blockIdx.x, tid = threadIdx.x;
  if (tid < 32) {
    int br = tid >> 4, k = tid & 15;
    int e = n * DEG + k;
    const int* a = br ? arc_out : arc_in;
    int l = (br ? lab_out : lab_in)[e];
    int srcn = a[e] * SS + a[EE + e];
    float g = (br ? xg_out : xg_in)[srcn] + (br ? b_outg : b_ing)[l];
    u_sl[tid] = 1 + br * LL + l;
    u_src[tid] = srcn;
    u_w[tid] = sigm(g) * (br ? mask_out : mask_in)[e];
  }
  __syncthreads();
  if (tid < 32) {
    int my = u_sl[tid];
    int rank = 0;
#pragma unroll
    for (int j = 0; j < 32; j++) {
      int oj = u_sl[j];
      rank += (oj < my || (oj == my && j < tid)) ? 1 : 0;
    }
    s_sl[rank] = my;
    s_src[rank] = u_src[tid];
    s_w[rank] = u_w[tid];
  }
  __syncthreads();

  const unsigned short* xp = (const unsigned short*)x;
  unsigned short* yp = (unsigned short*)Y;
  size_t base = (size_t)n * KTOT;
  int d4 = tid * 4;
  {
    float wl = sigm(xg_loop[n]) * mask_loop[n];
    ushort4 v = *(const ushort4*)&xp[(size_t)n * DD + d4];
    ushort4 o;
    o.x = f2bf(wl * bf2f(v.x)); o.y = f2bf(wl * bf2f(v.y));
    o.z = f2bf(wl * bf2f(v.z)); o.w = f2bf(wl * bf2f(v.w));
    *(ushort4*)&yp[base + d4] = o;
  }
  unsigned long long present = 0ull;
  float a0 = 0.f, a1 = 0.f, a2 = 0.f, a3 = 0.f, ws = 0.f;
#pragma unroll
  for (int e = 0; e < 32; e++) {
    int sl = s_sl[e];
    int srcn = s_src[e];
    float w = s_w[e];
    ushort4 v = *(const ushort4*)&xp[(size_t)srcn * DD + d4];
    a0 += w * bf2f(v.x); a1 += w * bf2f(v.y);
    a2 += w * bf2f(v.z); a3 += w * bf2f(v.w);
    ws += w;
    int slnext = (e < 31) ? s_sl[e + 1] : 999;
    if (sl != slnext) {
      ushort4 o;
      o.x = f2bf(a0); o.y = f2bf(a1); o.z = f2bf(a2); o.w = f2bf(a3);
      *(ushort4*)&yp[base + sl * DD + d4] = o;
      if (tid == 0) s_wsum[sl] = ws;
      present |= (1ull << sl);
      a0 = a1 = a2 = a3 = ws = 0.f;
    }
  }
  ushort4 zero4 = {0, 0, 0, 0};
#pragma unroll
  for (int s = 1; s < NSLICE; s++) {
    if (!((present >> s) & 1ull)) {
      *(ushort4*)&yp[base + s * DD + d4] = zero4;
      if (tid == 0) s_wsum[s] = 0.f;
    }
  }
  __syncthreads();
  {
    ushort4 o;
    unsigned short* op = (unsigned short*)&o;
#pragma unroll
    for (int c = 0; c < 4; c++) {
      int j = d4 + c;
      float v = (j >= 1 && j < NSLICE) ? s_wsum[j] : 0.f;
      op[c] = f2bf(v);
    }
    *(ushort4*)&yp[base + KMAIN + d4] = o;
  }
}

// ---------------------------------------------------------------------------
// K4: 256x256 8-phase bf16 MFMA GEMM — verbatim round-1 schedule (T2 swizzle
// both sides, raw s_barrier, counted vmcnt, setprio), with ONE change:
// MFMA operands SWAPPED (mfma(B,A) -> C^T fragments; proven R2/R3/R5) so the
// epilogue stores coalesced ushort4 (8 B/lane) instead of 128 scalar 2 B
// stores. grid (NN/TM=32, KSPLIT=8), 512 thr = 8 waves (2 wm x 4 wn).
// ---------------------------------------------------------------------------
__global__ __launch_bounds__(512, 2) void k_gemm(
    const __hip_bfloat16* __restrict__ A, const __hip_bfloat16* __restrict__ Bt,
    __hip_bfloat16* __restrict__ partial) {
  __shared__ __align__(16) __hip_bfloat16 As[2][TM * BK];
  __shared__ __align__(16) __hip_bfloat16 Bs[2][TN * BK];

  const int tid = threadIdx.x;
  const int w = tid >> 6, lane = tid & 63;
  const int wm = w >> 2, wn = w & 3;           // wave grid 2x4
  const int lrow = lane & 15, quad = lane >> 4;

  __hip_bfloat16* P = partial + (size_t)blockIdx.y * NN * UU;
  const int kbeg = blockIdx.y * KS;
  const int row0 = blockIdx.x * TM;

  // Staging: round r covers rows [r*64, r*64+64); thread tid writes LDS
  // bytes r*8192 + tid*16 (linear dest). Global source pre-swizzled (T2).
  const int arow = tid >> 3;                       // row within a 64-row round
  const int scol = ((tid & 7) ^ (arow & 7)) << 3;  // swizzled k-elem offset
  const __hip_bfloat16* srcA = A + (size_t)(row0 + arow) * KTOT + scol;
  const __hip_bfloat16* srcB = Bt + (size_t)arow * KTOT + scol;

  // ds_read swizzled k-slot offsets (elements) for the two k-halves
  const int sc0 = ((quad ^ (lrow & 7)) << 3);
  const int sc1 = (((4 + quad) ^ (lrow & 7)) << 3);

#define STG_A(bufi, k0, r)                                                 \
  GLDS(srcA + (size_t)((r) * 64) * KTOT + (k0),                            \
       &As[bufi][(r) * 4096 + (w << 9)])
#define STG_B(bufi, k0, r)                                                 \
  GLDS(srcB + (size_t)((r) * 64) * KTOT + (k0),                            \
       &Bs[bufi][(r) * 4096 + (w << 9)])
#define SBAR()                                                             \
  {                                                                        \
    asm volatile("" ::: "memory");                                         \
    __builtin_amdgcn_s_barrier();                                          \
    asm volatile("" ::: "memory");                                         \
  }
#define LGKM0()                                                            \
  {                                                                        \
    asm volatile("s_waitcnt lgkmcnt(0)" ::: "memory");                     \
    __builtin_amdgcn_sched_barrier(0);                                     \
  }
#define RD_A(DST, IBASE)                                                   \
  _Pragma("unroll")                                                        \
  for (int i = 0; i < 4; ++i) {                                            \
    int ro = (wm * 128 + ((IBASE) + i) * 16 + lrow) * BK;                  \
    DST[i][0] = *(const short8*)&as[ro + sc0];                             \
    DST[i][1] = *(const short8*)&as[ro + sc1];                             \
  }
#define RD_B(DST, JBASE)                                                   \
  _Pragma("unroll")                                                        \
  for (int j = 0; j < 2; ++j) {                                            \
    int ro = (wn * 64 + ((JBASE) + j) * 16 + lrow) * BK;                   \
    DST[j][0] = *(const short8*)&bs[ro + sc0];                             \
    DST[j][1] = *(const short8*)&bs[ro + sc1];                             \
  }
// operands swapped: D = B_frag x A_frag = C^T fragments (proven R2/R3/R5)
#define MFMA16(AF, BF, IOFF, JOFF)                                         \
  {                                                                        \
    __builtin_amdgcn_s_setprio(1);                                         \
    _Pragma("unroll")                                                      \
    for (int i = 0; i < 4; ++i)                                            \
      _Pragma("unroll")                                                    \
      for (int j = 0; j < 2; ++j) {                                        \
        acc[(IOFF) + i][(JOFF) + j] =                                      \
            __builtin_amdgcn_mfma_f32_16x16x32_bf16(                       \
                BF[j][0], AF[i][0], acc[(IOFF) + i][(JOFF) + j], 0, 0, 0); \
        acc[(IOFF) + i][(JOFF) + j] =                                      \
            __builtin_amdgcn_mfma_f32_16x16x32_bf16(                       \
                BF[j][1], AF[i][1], acc[(IOFF) + i][(JOFF) + j], 0, 0, 0); \
      }                                                                    \
    __builtin_amdgcn_s_setprio(0);                                         \
  }

  // Prologue: stage tile0 -> buf0, tile1 -> buf1; wait tile0 (8 newest = t1).
#pragma unroll
  for (int r = 0; r < 4; ++r) STG_A(0, kbeg, r);
#pragma unroll
  for (int r = 0; r < 4; ++r) STG_B(0, kbeg, r);
#pragma unroll
  for (int r = 0; r < 4; ++r) STG_A(1, kbeg + BK, r);
#pragma unroll
  for (int r = 0; r < 4; ++r) STG_B(1, kbeg + BK, r);
  f32x4 acc[8][4] = {};
  asm volatile("s_waitcnt vmcnt(8)" ::: "memory");
  SBAR();

  for (int t = 0; t < NTILES; ++t) {
    const int bi = t & 1;
    const __hip_bfloat16* as = &As[bi][0];
    const __hip_bfloat16* bs = &Bs[bi][0];
    const bool st = (t + 2 < NTILES);
    const int kn = kbeg + (t + 2) * BK;
    short8 afA[4][2], afB[4][2], bfA[2][2], bfB[2][2];

    // ---- P1: read af[0..3], bf[0..1]; MFMA Q0 ----
    RD_A(afA, 0);
    RD_B(bfA, 0);
    SBAR();
    LGKM0();
    MFMA16(afA, bfA, 0, 0);
    SBAR();

    // ---- P2: read bf[2..3]; stage A rounds 0,2; MFMA Q1 ----
    RD_B(bfB, 2);
    if (st) { STG_A(bi, kn, 0); STG_A(bi, kn, 2); }
    SBAR();
    LGKM0();
    MFMA16(afA, bfB, 0, 2);
    SBAR();

    // ---- P3: read af[4..7]; stage B rounds 0..3; MFMA Q2 ----
    RD_A(afB, 4);
    if (st) { STG_B(bi, kn, 0); STG_B(bi, kn, 1); STG_B(bi, kn, 2); STG_B(bi, kn, 3); }
    SBAR();
    LGKM0();
    MFMA16(afB, bfA, 4, 0);
    SBAR();

    // ---- P4: stage A rounds 1,3; MFMA Q3; counted vmcnt ----
    if (st) {
      STG_A(bi, kn, 1);
      STG_A(bi, kn, 3);
      __builtin_amdgcn_sched_barrier(0);
    }
    SBAR();
    MFMA16(afB, bfB, 4, 2);
    if (st) asm volatile("s_waitcnt vmcnt(8)" ::: "memory");
    else    asm volatile("s_waitcnt vmcnt(0)" ::: "memory");
    SBAR();
  }
#undef STG_A
#undef STG_B
#undef SBAR
#undef LGKM0
#undef RD_A
#undef RD_B
#undef MFMA16

  // Swapped C/D layout: lane owns row n = ...+lrow, u = j*16 + quad*4..+3
  unsigned short* Pp = (unsigned short*)P;
#pragma unroll
  for (int i = 0; i < 8; ++i)
#pragma unroll
    for (int j = 0; j < 4; ++j) {
      int nr = row0 + wm * 128 + i * 16 + lrow;
      int u0 = wn * 64 + j * 16 + quad * 4;
      ushort4 o;
      o.x = f2bf(acc[i][j][0]); o.y = f2bf(acc[i][j][1]);
      o.z = f2bf(acc[i][j][2]); o.w = f2bf(acc[i][j][3]);
      *(ushort4*)&Pp[(size_t)nr * UU + u0] = o;
    }
}

// ---------------------------------------------------------------------------
// K5: reduce KSPLIT bf16 partials + relu + sent_mask + transpose (round-0).
// ---------------------------------------------------------------------------
__global__ __launch_bounds__(64) void k_finish(
    const __hip_bfloat16* __restrict__ partial, const float* __restrict__ sent,
    float* __restrict__ out) {
  int n = blockIdx.x, u4 = threadIdx.x * 4;
  size_t idx = (size_t)n * UU + u4;
  const unsigned short* pp = (const unsigned short*)partial;
  float a0 = 0.f, a1 = 0.f, a2 = 0.f, a3 = 0.f;
#pragma unroll
  for (int z = 0; z < KSPLIT; z++) {
    ushort4 v = *(const ushort4*)&pp[(size_t)z * NN * UU + idx];
    a0 += bf2f(v.x); a1 += bf2f(v.y); a2 += bf2f(v.z); a3 += bf2f(v.w);
  }
  int s = n % SS, b = n / SS;
  float sm = sent[s * BB + b];
  float4 o;
  o.x = fmaxf(a0, 0.f) * sm; o.y = fmaxf(a1, 0.f) * sm;
  o.z = fmaxf(a2, 0.f) * sm; o.w = fmaxf(a3, 0.f) * sm;
  *(float4*)&out[((size_t)s * BB + b) * UU + u4] = o;
}

extern "C" void kernel_launch(void* const* d_in, const int* in_sizes, int n_in,
                              void* d_out, int out_size, void* d_ws, size_t ws_size,
                              hipStream_t stream) {
  const float* src      = (const float*)d_in[0];
  const float* V_in     = (const float*)d_in[1];
  const float* b_in     = (const float*)d_in[2];
  const float* V_ing    = (const float*)d_in[3];
  const float* b_ing    = (const float*)d_in[4];
  const float* V_out    = (const float*)d_in[5];
  const float* b_out    = (const float*)d_in[6];
  const float* V_outg   = (const float*)d_in[7];
  const float* b_outg   = (const float*)d_in[8];
  const float* W_self   = (const float*)d_in[9];
  const float* W_selfg  = (const float*)d_in[10];
  const int* arc_in     = (const int*)d_in[11];
  const int* arc_out    = (const int*)d_in[12];
  const int* lab_in     = (const int*)d_in[13];
  const int* lab_out    = (const int*)d_in[14];
  const float* mask_in  = (const float*)d_in[15];
  const float* mask_out = (const float*)d_in[16];
  const float* mask_loop= (const float*)d_in[17];
  const float* sent     = (const float*)d_in[18];
  float* out = (float*)d_out;

  char* ws = (char*)d_ws;
  size_t off = 0;
  auto alloc = [&](size_t bytes) -> void* {
    void* p = ws + off;
    off += (bytes + 255) & ~(size_t)255;
    return p;
  };
  __hip_bfloat16* x_bf = (__hip_bfloat16*)alloc((size_t)NN * DD * 2);       // 4 MB
  __hip_bfloat16* Vt   = (__hip_bfloat16*)alloc((size_t)UU * KTOT * 2);     // 4.5 MB
  float* xg_in   = (float*)alloc(NN * 4);
  float* xg_out  = (float*)alloc(NN * 4);
  float* xg_loop = (float*)alloc(NN * 4);
  __hip_bfloat16* Y = (__hip_bfloat16*)alloc((size_t)NN * KTOT * 2);        // 143 MB
  __hip_bfloat16* partial =
      (__hip_bfloat16*)alloc((size_t)KSPLIT * NN * UU * 2);                 // 34 MB

  k_pre<<<NN + (NSLICE + 1) * 64, 256, 0, stream>>>(
      src, V_ing, V_outg, W_selfg, V_in, V_out, W_self, b_in, b_out,
      x_bf, xg_in, xg_out, xg_loop, Vt);
  k_agg<<<NN, 64, 0, stream>>>(x_bf, xg_in, xg_out, xg_loop, b_ing, b_outg,
                               arc_in, arc_out, lab_in, lab_out,
                               mask_in, mask_out, mask_loop, Y);
  k_gemm<<<dim3(NN / TM, KSPLIT), 512, 0, stream>>>(Y, Vt, partial);
  k_finish<<<NN, 64, 0, stream>>>(partial, sent, out);
}